// Round 2
// baseline (213.501 us; speedup 1.0000x reference)
//
#include <hip/hip_runtime.h>
#include <hip/hip_bf16.h>

// HyperbolicMapper: LayerNorm -> spectral-norm linear (K=16) -> scale -> Poincare expmap0
// N=65536, D=4096, K=16. Memory-bound on reading x (1 GiB fp32).
// Roofline: ~1.078 GB / 6.5 TB/s ~= 166 us.

#define ND 4096
#define NK 16
#define NROWS 65536

using f32x4  = __attribute__((ext_vector_type(4))) float;
using bf16x8 = __attribute__((ext_vector_type(8))) short;

// workspace byte offsets
#define GWB_OFF  0u        // ushort[ND*NK] = 128 KB, gamma*W bf16, MFMA-B-fragment layout
#define SC_OFF   131072u   // float[33] : coef, G[16], B[16]

__device__ __forceinline__ unsigned short f2bf(float f) {
    union { __hip_bfloat16 h; unsigned short u; } cv;
    cv.h = __float2bfloat16(f);
    return cv.u;
}

// ---------------- fused prep: one block x 1024 threads ----------------
// Phase 1: t = W^T u; gwb = bf16(gamma*W) in B-frag layout; partials of
//          nt2=||t||^2, G[k]=sum gamma*W, B[k]=sum beta*W.
// Phase 2: v = t/||t||; sp = W v; sigma = ||Wv||^2/(||Wv||+eps); sc scalars.
__global__ __launch_bounds__(1024) void prep(
    const float* __restrict__ W, const float* __restrict__ gamma,
    const float* __restrict__ beta, const float* __restrict__ u,
    const float* __restrict__ log_scale,
    unsigned short* __restrict__ ws_gwb, float* __restrict__ sc)
{
    const int tid = threadIdx.x;
    const int lane = tid & 63, wid = tid >> 6;
    __shared__ float t_sh[ND];        // 16 KB
    __shared__ float wred[16][34];
    __shared__ float tot[34];

    float uu[NK];
#pragma unroll
    for (int k = 0; k < NK; ++k) uu[k] = u[k];

    const int d0 = tid * 4;
    const f32x4 g4 = *(const f32x4*)(gamma + d0);
    const f32x4 b4 = *(const f32x4*)(beta + d0);

    f32x4 t4 = {0.f, 0.f, 0.f, 0.f};
    float G[NK], B[NK];
    const int c8 = tid >> 1;
    const int j0 = (tid & 1) * 4;
#pragma unroll
    for (int k = 0; k < NK; ++k) {
        const f32x4 w4 = *(const f32x4*)(W + k * ND + d0);
        t4[0] = fmaf(w4[0], uu[k], t4[0]);
        t4[1] = fmaf(w4[1], uu[k], t4[1]);
        t4[2] = fmaf(w4[2], uu[k], t4[2]);
        t4[3] = fmaf(w4[3], uu[k], t4[3]);
        const float gw0 = g4[0]*w4[0], gw1 = g4[1]*w4[1], gw2 = g4[2]*w4[2], gw3 = g4[3]*w4[3];
        G[k] = (gw0 + gw1) + (gw2 + gw3);
        B[k] = (b4[0]*w4[0] + b4[1]*w4[1]) + (b4[2]*w4[2] + b4[3]*w4[3]);
        ushort4 st;
        st.x = f2bf(gw0); st.y = f2bf(gw1); st.z = f2bf(gw2); st.w = f2bf(gw3);
        *(ushort4*)(ws_gwb + (c8 * NK + k) * 8 + j0) = st;
    }
    *(f32x4*)(t_sh + d0) = t4;
    float nt2 = (t4[0]*t4[0] + t4[1]*t4[1]) + (t4[2]*t4[2] + t4[3]*t4[3]);
#pragma unroll
    for (int m = 1; m < 64; m <<= 1) {
        nt2 += __shfl_xor(nt2, m);
#pragma unroll
        for (int k = 0; k < NK; ++k) {
            G[k] += __shfl_xor(G[k], m);
            B[k] += __shfl_xor(B[k], m);
        }
    }
    if (lane == 0) {
        wred[wid][0] = nt2;
#pragma unroll
        for (int k = 0; k < NK; ++k) { wred[wid][1 + k] = G[k]; wred[wid][17 + k] = B[k]; }
    }
    __syncthreads();
    if (tid < 33) {
        float s = 0.f;
        for (int w = 0; w < 16; ++w) s += wred[w][tid];
        tot[tid] = s;
    }
    __syncthreads();
    const float inv_nt = 1.0f / (sqrtf(tot[0]) + 1e-12f);
    f32x4 tv = *(const f32x4*)(t_sh + d0);
    tv[0] *= inv_nt; tv[1] *= inv_nt; tv[2] *= inv_nt; tv[3] *= inv_nt;
    float sp[NK];
#pragma unroll
    for (int k = 0; k < NK; ++k) {
        const f32x4 w4 = *(const f32x4*)(W + k * ND + d0);   // L2-hot re-read
        sp[k] = (w4[0]*tv[0] + w4[1]*tv[1]) + (w4[2]*tv[2] + w4[3]*tv[3]);
    }
#pragma unroll
    for (int m = 1; m < 64; m <<= 1) {
#pragma unroll
        for (int k = 0; k < NK; ++k) sp[k] += __shfl_xor(sp[k], m);
    }
    __syncthreads();   // wred reuse guard
    if (lane == 0) {
#pragma unroll
        for (int k = 0; k < NK; ++k) wred[wid][k] = sp[k];
    }
    __syncthreads();
    if (tid == 0) {
        float ns2 = 0.f;
        for (int k = 0; k < NK; ++k) {
            float s = 0.f;
            for (int w = 0; w < 16; ++w) s += wred[w][k];
            ns2 += s * s;
        }
        const float sigma = ns2 / (sqrtf(ns2) + 1e-12f);
        const float scale = 0.5f / (1.0f + expf(-log_scale[0]));  // sigmoid*0.5
        sc[0] = scale / sigma;
#pragma unroll
        for (int k = 0; k < NK; ++k) { sc[1 + k] = tot[1 + k]; sc[17 + k] = tot[17 + k]; }
    }
}

// ---------------- main: one pass over x, MFMA 16x16x32 bf16 ----------------
// 256 blocks x 1024 threads; 16 waves/block; wave <-> one 16-row tile.
// A-frag: x rows (fp32 nt-load, converted to bf16 in-register); lane l supplies
//   A[row = l&15][kk = (l>>4)*8 + j].
// B-frag: gamma*W bf16 staged in LDS; lane address = 16*lane + 32*c bytes
//   (linear, conflict-free); supplies B[kk][col = k = l&15].
// C: col = lane&15 (k), row = (lane>>4)*4 + reg  [m89-verified].
__global__ __launch_bounds__(1024, 4) void hyp_main(
    const float* __restrict__ x, const unsigned short* __restrict__ gwb_g,
    const float* __restrict__ sc, float* __restrict__ out)
{
    __shared__ unsigned short gwb[ND * NK];  // 128 KB

    const int lane = threadIdx.x & 63;
    const int wid  = threadIdx.x >> 6;
    const int tile = (blockIdx.x << 4) + wid;   // 0..4095, one per wave
    const int lr = lane & 15;                   // A-row within tile / C-col (k)
    const int lc = lane >> 4;                   // kk-group / C-row group

    const float* xp = x + (size_t)(tile * 16 + lr) * ND + lc * 8;
    const unsigned short* lp = gwb + lane * 8;  // + c*16 ushorts per step

    // issue iter-0 x loads BEFORE the LDS staging so HBM starts immediately
    f32x4 xa = __builtin_nontemporal_load((const f32x4*)xp);
    f32x4 xb = __builtin_nontemporal_load((const f32x4*)(xp + 4));

    {
        const uint4* src = (const uint4*)gwb_g;
        uint4* dst = (uint4*)gwb;
#pragma unroll
        for (int i = 0; i < 8; ++i)
            dst[threadIdx.x + i * 1024] = src[threadIdx.x + i * 1024];
    }
    __syncthreads();

    // epilogue scalars: issue early, used late
    const float coef = sc[0];
    const float gk = sc[1 + lr];   // G[k], k = lane&15 = C-col
    const float bk = sc[17 + lr];  // B[k]

    f32x4 acc = {0.f, 0.f, 0.f, 0.f};
    float s1 = 0.f, s2 = 0.f;

#define PROCESS(XA, XB, CC) do {                                          \
        bf16x8 afrag;                                                     \
        afrag[0] = (short)f2bf(XA[0]); afrag[1] = (short)f2bf(XA[1]);     \
        afrag[2] = (short)f2bf(XA[2]); afrag[3] = (short)f2bf(XA[3]);     \
        afrag[4] = (short)f2bf(XB[0]); afrag[5] = (short)f2bf(XB[1]);     \
        afrag[6] = (short)f2bf(XB[2]); afrag[7] = (short)f2bf(XB[3]);     \
        s1 += ((XA[0] + XA[1]) + (XA[2] + XA[3]))                         \
            + ((XB[0] + XB[1]) + (XB[2] + XB[3]));                        \
        s2 = fmaf(XA[0], XA[0], s2); s2 = fmaf(XA[1], XA[1], s2);         \
        s2 = fmaf(XA[2], XA[2], s2); s2 = fmaf(XA[3], XA[3], s2);         \
        s2 = fmaf(XB[0], XB[0], s2); s2 = fmaf(XB[1], XB[1], s2);         \
        s2 = fmaf(XB[2], XB[2], s2); s2 = fmaf(XB[3], XB[3], s2);         \
        bf16x8 bfrag = *(const bf16x8*)(lp + (CC) * 16);                  \
        acc = __builtin_amdgcn_mfma_f32_16x16x32_bf16(afrag, bfrag, acc, 0, 0, 0); \
    } while (0)

    // rotated software-prefetch: load c+32 while processing c
#pragma unroll 4
    for (int c = 0; c < ND - 32; c += 32) {
        f32x4 na = __builtin_nontemporal_load((const f32x4*)(xp + c + 32));
        f32x4 nb = __builtin_nontemporal_load((const f32x4*)(xp + c + 36));
        PROCESS(xa, xb, c);
        xa = na; xb = nb;
    }
    PROCESS(xa, xb, ND - 32);
#undef PROCESS

    // S1/S2 for row lr: reduce across the 4 lanes {l, l^16, l^32, l^48}
    s1 += __shfl_xor(s1, 16); s1 += __shfl_xor(s1, 32);
    s2 += __shfl_xor(s2, 16); s2 += __shfl_xor(s2, 32);
    const float mean = s1 * (1.0f / ND);
    const float var  = s2 * (1.0f / ND) - mean * mean;
    const float rstd = rsqrtf(var + 1e-5f);

    float vout[4];
#pragma unroll
    for (int j = 0; j < 4; ++j) {
        const int r = lc * 4 + j;              // C-row within tile
        const float m_r  = __shfl(mean, r);    // stats live in lane r (r<16)
        const float rs_r = __shfl(rstd, r);
        vout[j] = coef * (fmaf(-m_r, gk, acc[j]) * rs_r + bk);
    }

    // row-norm over k: reduce across the 16 lanes sharing lc (xor masks 1,2,4,8)
    float nsq[4];
#pragma unroll
    for (int j = 0; j < 4; ++j) nsq[j] = vout[j] * vout[j];
#pragma unroll
    for (int m = 1; m < 16; m <<= 1) {
#pragma unroll
        for (int j = 0; j < 4; ++j) nsq[j] += __shfl_xor(nsq[j], m);
    }

#pragma unroll
    for (int j = 0; j < 4; ++j) {
        float nv = sqrtf(nsq[j]);
        nv = fmaxf(nv, 1e-15f);
        const float fac = tanhf(nv) / nv;
        __builtin_nontemporal_store(vout[j] * fac,
            out + (size_t)(tile * 16 + lc * 4 + j) * NK + lr);
    }
}

extern "C" void kernel_launch(void* const* d_in, const int* in_sizes, int n_in,
                              void* d_out, int out_size, void* d_ws, size_t ws_size,
                              hipStream_t stream) {
    const float* x     = (const float*)d_in[0];
    const float* gamma = (const float*)d_in[1];
    const float* beta  = (const float*)d_in[2];
    const float* W     = (const float*)d_in[3];
    const float* u     = (const float*)d_in[4];
    const float* ls    = (const float*)d_in[5];

    char* ws = (char*)d_ws;
    unsigned short* ws_gwb = (unsigned short*)(ws + GWB_OFF);
    float* sc      = (float*)(ws + SC_OFF);
    float* out     = (float*)d_out;

    prep<<<1, 1024, 0, stream>>>(W, gamma, beta, u, ls, ws_gwb, sc);
    hyp_main<<<256, 1024, 0, stream>>>(x, ws_gwb, sc, out);
}